// Round 1
// baseline (288.886 us; speedup 1.0000x reference)
//
#include <hip/hip_runtime.h>

// ---------------------------------------------------------------------------
// ConvCaps (EM routing): b=8, B=32, C=32, K=3, stride=2, Win=13, Wout=6, 3 iters
// x: (8, 544, 13, 13) f32   [pose 512ch = (q,r,o), act 32ch]
// W: (3,3,32,32,4,4) f32    [i,j,o,c,p,q]
// out: (8, 544, 6, 6) f32   [c*16+d poses, then 32 acts]
// vote[d = p*4+r] = sum_q W[i,j,o,c,p,q] * pose[n,q,r,o,2x+i,2y+j]
// ---------------------------------------------------------------------------

#define NPARENT 9216           // 8*6*6*32  (n,x,y,c)
#define NCHILD  288            // 32*9      (o,i,j) per parent
#define NCHILD_GLOBAL 82944    // 8*6*6*288
#define NPAIR   2654208        // NPARENT*288 = NCHILD_GLOBAL*32

// workspace layout (floats)
#define OFF_PHAT 0
#define OFF_D    2654208       // 8*32*13*13 = 43264
#define OFF_MU   2697472       // 9216*16 = 147456
#define OFF_S    2844928       // 9216
#define OFF_ACT  2854144       // 9216
#define OFF_POST 2863360       // 8*32*169*16 = 692224
// total = 3555584 floats = 14.2 MB

__device__ __forceinline__ float wred64(float v) {
#pragma unroll
  for (int m = 32; m >= 1; m >>= 1) v += __shfl_xor(v, m, 64);
  return v;
}

__device__ __forceinline__ void load16(const float* __restrict__ p, float* dst) {
  const float4* p4 = (const float4*)p;
  float4 a = p4[0], b = p4[1], c = p4[2], d = p4[3];
  dst[0]=a.x; dst[1]=a.y; dst[2]=a.z; dst[3]=a.w;
  dst[4]=b.x; dst[5]=b.y; dst[6]=b.z; dst[7]=b.w;
  dst[8]=c.x; dst[9]=c.y; dst[10]=c.z; dst[11]=c.w;
  dst[12]=d.x; dst[13]=d.y; dst[14]=d.z; dst[15]=d.w;
}

// transpose pose: x[n, (q*4+r)*32+o, pix] -> posT[(n*32+o)*169+pix][d=q*4+r]
__global__ __launch_bounds__(256) void prep_kernel(const float* __restrict__ x,
                                                   float* __restrict__ posT) {
  int tid = blockIdx.x * 256 + threadIdx.x;   // 692224 = 2704*256
  int pix = tid % 169; int t = tid / 169;
  int o = t & 31; t >>= 5;
  int d = t & 15; int n = t >> 4;
  float v = x[((size_t)n * 544 + d * 32 + o) * 169 + pix];
  posT[((size_t)(n * 32 + o) * 169 + pix) * 16 + d] = v;
}

// M-step: one wave per parent (n,x,y,c).
// mode 0: first iter (Rp uniform), write mu/S/act
// mode 1: Rp = p_hat/D,            write mu/S/act
// mode 2: Rp = p_hat/D,            write final output
__global__ __launch_bounds__(64) void mstep_kernel(
    const float* __restrict__ x, const float* __restrict__ Wt,
    const float* __restrict__ posT,
    const float* __restrict__ p_hat, const float* __restrict__ Dbuf,
    float* __restrict__ mu_out, float* __restrict__ S_out,
    float* __restrict__ act_out,
    const float* __restrict__ beta_v, const float* __restrict__ beta_a,
    const float* __restrict__ lambda_, float* __restrict__ out, int mode) {
  const int pid = blockIdx.x;
  const int c = pid & 31;
  int t = pid >> 5;
  const int y = t % 6; t /= 6;
  const int xx = t % 6;
  const int n = t / 6;
  const int lane = threadIdx.x;

  float sum_r = 0.f;
  float sv[16], sq[16];
#pragma unroll
  for (int d = 0; d < 16; ++d) { sv[d] = 0.f; sq[d] = 0.f; }

  const float* xn = x + (size_t)n * (544 * 169);
  const float* phb = p_hat + (size_t)pid * NCHILD;

#pragma unroll
  for (int k = 0; k < 5; ++k) {
    int ch = lane + 64 * k;
    const bool active = (ch < NCHILD);
    if (!active) ch = 0;
    const int o = ch / 9;
    const int ij = ch - o * 9;
    const int i = ij / 3, j = ij - i * 3;
    const int row = 2 * xx + i, col = 2 * y + j;

    float P[16];
    load16(posT + ((size_t)(n * 32 + o) * 169 + row * 13 + col) * 16, P);
    float Wm[16];
    load16(Wt + (size_t)((ij * 32 + o) * 32 + c) * 16, Wm);

    float a = xn[(size_t)(512 + o) * 169 + row * 13 + col];
    float rhat;
    if (mode == 0) {
      rhat = a * (1.0f / 1152.0f);
    } else {
      float ph = phb[ch];
      float Dg = Dbuf[((n * 32 + o) * 13 + row) * 13 + col];
      rhat = (ph / Dg) * a;
    }
    if (!active) rhat = 0.f;
    sum_r += rhat;
#pragma unroll
    for (int p = 0; p < 4; ++p)
#pragma unroll
      for (int r = 0; r < 4; ++r) {
        float v = Wm[p * 4 + 0] * P[0 + r] + Wm[p * 4 + 1] * P[4 + r] +
                  Wm[p * 4 + 2] * P[8 + r] + Wm[p * 4 + 3] * P[12 + r];
        sv[p * 4 + r] = fmaf(rhat, v, sv[p * 4 + r]);
        sq[p * 4 + r] = fmaf(rhat * v, v, sq[p * 4 + r]);
      }
  }

  sum_r = wred64(sum_r);
  const float inv_sr = 1.0f / sum_r;
  float mu[16], sig[16];
#pragma unroll
  for (int d = 0; d < 16; ++d) {
    float s1 = wred64(sv[d]);
    float s2 = wred64(sq[d]);
    float m = s1 * inv_sr;
    mu[d] = m;
    sig[d] = fmaxf(s2 * inv_sr - m * m, 1e-30f);
  }

  const float bv = beta_v[0], ba = beta_a[0], lam = lambda_[0];
  float lsum = 0.f;
#pragma unroll
  for (int d = 0; d < 16; ++d) lsum += __logf(sig[d]);
  const float cost = (16.f * bv + lsum) * sum_r;
  const float z = lam * (ba - cost);
  const float aout = 1.0f / (1.0f + __expf(-z));

  if (lane == 0) {
    if (mode == 2) {
      float* ob = out + (size_t)(n * 544 + c * 16) * 36 + xx * 6 + y;
#pragma unroll
      for (int d = 0; d < 16; ++d) ob[d * 36] = mu[d];
      out[(size_t)(n * 544 + 512 + c) * 36 + xx * 6 + y] = aout;
    } else {
      float* mb = mu_out + (size_t)pid * 16;
#pragma unroll
      for (int d = 0; d < 16; ++d) mb[d] = mu[d];
      S_out[pid] = lsum + 16.f * 1.8378770664093453f;  // + 16*log(2*pi)
      act_out[pid] = aout;
    }
  }
}

// E-step: thread per (child, c) pair. Group of 32 lanes = one child.
__global__ __launch_bounds__(64) void estep_kernel(
    const float* __restrict__ Wt, const float* __restrict__ posT,
    float* __restrict__ p_hat, float* __restrict__ Dbuf,
    const float* __restrict__ mu_arr, const float* __restrict__ S_arr,
    const float* __restrict__ act_arr) {
  const int gp = blockIdx.x * 64 + threadIdx.x;   // 2654208 = 41472*64
  const int c = gp & 31;
  int child = gp >> 5;
  const int ij = child % 9; int t = child / 9;
  const int o = t & 31; t >>= 5;
  const int y = t % 6; t /= 6;
  const int xx = t % 6;
  const int n = t / 6;
  const int i = ij / 3, j = ij - i * 3;
  const int i2 = (i == 0) ? 0 : 3 - i;   // kperm = {0,2,1}
  const int j2 = (j == 0) ? 0 : 3 - j;
  const int row2 = 2 * xx + i2, col2 = 2 * y + j2;

  float P[16];
  load16(posT + ((size_t)(n * 32 + o) * 169 + row2 * 13 + col2) * 16, P);
  float Wm[16];
  load16(Wt + (size_t)(((i2 * 3 + j2) * 32 + o) * 32 + c) * 16, Wm);

  const int pid = ((n * 6 + xx) * 6 + y) * 32 + c;
  float mu[16];
  load16(mu_arr + (size_t)pid * 16, mu);

  float sumsq = 0.f;
#pragma unroll
  for (int p = 0; p < 4; ++p)
#pragma unroll
    for (int r = 0; r < 4; ++r) {
      float v = Wm[p * 4 + 0] * P[0 + r] + Wm[p * 4 + 1] * P[4 + r] +
                Wm[p * 4 + 2] * P[8 + r] + Wm[p * 4 + 3] * P[12 + r];
      float dv = v - mu[p * 4 + r];
      sumsq = fmaf(dv, dv, sumsq);
    }

  const float pr = __expf(-sumsq - 0.5f * S_arr[pid]);
  const float ph = act_arr[pid] * pr;
  p_hat[(size_t)pid * NCHILD + o * 9 + ij] = ph;

  float T = ph;
#pragma unroll
  for (int m = 16; m >= 1; m >>= 1) T += __shfl_xor(T, m, 32);
  if (c == 0)
    atomicAdd(&Dbuf[((n * 32 + o) * 13 + 2 * xx + i) * 13 + 2 * y + j], T);
}

extern "C" void kernel_launch(void* const* d_in, const int* in_sizes, int n_in,
                              void* d_out, int out_size, void* d_ws,
                              size_t ws_size, hipStream_t stream) {
  const float* x   = (const float*)d_in[0];
  const float* Wt  = (const float*)d_in[1];
  const float* bv  = (const float*)d_in[2];
  const float* ba  = (const float*)d_in[3];
  const float* lam = (const float*)d_in[4];
  float* out = (float*)d_out;
  float* ws = (float*)d_ws;

  float* p_hat = ws + OFF_PHAT;
  float* Dbuf  = ws + OFF_D;
  float* mu    = ws + OFF_MU;
  float* S     = ws + OFF_S;
  float* act   = ws + OFF_ACT;
  float* posT  = ws + OFF_POST;

  (void)in_sizes; (void)n_in; (void)out_size; (void)ws_size;

  prep_kernel<<<2704, 256, 0, stream>>>(x, posT);
  hipMemsetAsync(Dbuf, 0, 43264 * sizeof(float), stream);

  // iter 0
  mstep_kernel<<<NPARENT, 64, 0, stream>>>(x, Wt, posT, p_hat, Dbuf, mu, S, act,
                                           bv, ba, lam, out, 0);
  estep_kernel<<<NPAIR / 64, 64, 0, stream>>>(Wt, posT, p_hat, Dbuf, mu, S, act);
  // iter 1
  mstep_kernel<<<NPARENT, 64, 0, stream>>>(x, Wt, posT, p_hat, Dbuf, mu, S, act,
                                           bv, ba, lam, out, 1);
  hipMemsetAsync(Dbuf, 0, 43264 * sizeof(float), stream);
  estep_kernel<<<NPAIR / 64, 64, 0, stream>>>(Wt, posT, p_hat, Dbuf, mu, S, act);
  // iter 2 (final, writes output)
  mstep_kernel<<<NPARENT, 64, 0, stream>>>(x, Wt, posT, p_hat, Dbuf, mu, S, act,
                                           bv, ba, lam, out, 2);
}